// Round 7
// baseline (698.864 us; speedup 1.0000x reference)
//
#include <hip/hip_runtime.h>

#define NN 20
#define ST 22          // stride for 20-row fp64 tiles; rows 16B-aligned (b128-friendly)
#define N2 400
#define MM 440
#define NITERS 25
#define NQ 2           // problems per wave

// single-wave block + per-wave in-order LDS pipeline => compiler fence suffices
#define FENCE() asm volatile("" ::: "memory")

__device__ __forceinline__ double drcp(double x) {
  double r = __builtin_amdgcn_rcp(x);       // v_rcp_f64 seed
  r = fma(r, fma(-x, r, 1.0), r);           // NR 1
  r = fma(r, fma(-x, r, 1.0), r);           // NR 2 -> ~1 ulp (seed may be f16-grade!)
  return r;
}
__device__ __forceinline__ double dreadlane(double v, int lane) {
  int lo = __builtin_amdgcn_readlane(__double2loint(v), lane);
  int hi = __builtin_amdgcn_readlane(__double2hiint(v), lane);
  return __hiloint2double(hi, lo);
}
__device__ __forceinline__ double wsumd(double v) {
#pragma unroll
  for (int off = 32; off > 0; off >>= 1) v += __shfl_xor(v, off, 64);
  return v;
}
__device__ __forceinline__ double fair_d(int c) {
  return (c < 8) ? 0.125 : (double)(-1.0f / 12.0f);  // matches fp32 ref constant
}

__global__ __launch_bounds__(64, 1) void ipm_kernel(const float* __restrict__ x,
                                                    float* __restrict__ out) {
  const int b = blockIdx.x;   // 16 blocks, problems 2b and 2b+1
  const int t = threadIdx.x;

  __shared__ __align__(16) double phim[NQ][NN * ST];
  __shared__ __align__(16) double phimT[NQ][NN * ST];
  __shared__ __align__(16) double y1m[NQ][NN * ST];
  __shared__ __align__(16) double y1T[NQ][NN * ST];
  __shared__ __align__(16) double phiDT[NQ][NN * ST];
  __shared__ __align__(16) double SmX[NQ][NN * ST];  // row c: [S[c][0..19] | rb1 rb2]
  __shared__ __align__(16) double glrc[NQ][40];
  __shared__ __align__(16) double D1iv[NQ][NN], D2vv[NQ][NN];
  __shared__ __align__(16) double p1v[NQ][NN], p2v[NQ][NN], t1v[NQ][NN], Ccv[NQ][NN];
  __shared__ __align__(16) double a1G[NQ][NN], a2G[NQ][NN];
  __shared__ __align__(16) double be1v[NQ][NN], be2v[NQ][NN];
  __shared__ __align__(16) double a1rv[NQ][NN], a2rv[NQ][NN], PB1v[NQ][NN], PB2v[NQ][NN];

  const double EPSd = 1e-4, SIG = 0.1;

  // element state: element i = t + 64*j (j=0..6); s_slack == z exactly (identical updates)
  double zr[NQ][7], pr[NQ][7], sl[NQ][7];
  double srs[NQ][7], du1[NQ][7], du2[NQ][7], dzr[NQ][7], sdl[NQ][7];
  int rr_[7], cc_[7];
  // row/col constraint state on lanes t<40 (rows 0..19, cols 20..39); r_pri == 0 identity
  double s1[NQ], l1[NQ], rs1[NQ], ds1[NQ], dl1[NQ], invd[NQ];
  double e0[NQ], e1[NQ], e2[NQ], D1iloc[NQ], W1[NQ], W2[NQ], sumdz[NQ];
  double nu[NQ], req[NQ], musum[NQ], smu[NQ];

#pragma unroll
  for (int j = 0; j < 7; ++j) {
    int i = t + 64 * j;
    if (i < N2) {
      int r = i / NN, c = i - (i / NN) * NN;
      rr_[j] = r; cc_[j] = c;
    } else { rr_[j] = 0; cc_[j] = 0; }
  }
#pragma unroll
  for (int q = 0; q < NQ; ++q) {
    double lreq0 = 0.0;
#pragma unroll
    for (int j = 0; j < 7; ++j) {
      int i = t + 64 * j;
      if (i < N2) {
        zr[q][j] = 0.025;
        pr[q][j] = -(double)x[(2 * b + q) * N2 + i];
        sl[q][j] = 1.0;
        lreq0 += fair_d(cc_[j]) * 0.025;
      }
    }
    req[q] = wsumd(lreq0);
    nu[q] = 0.0;
    musum[q] = 30.0;                 // exact: 40*0.5*1 + 400*0.025*1
    smu[q] = SIG * 30.0 * (1.0 / MM);
    s1[q] = 0.5; l1[q] = 1.0;
  }

#pragma unroll 1
  for (int it = 0; it < NITERS; ++it) {
    // ---- C: per-constraint scalars (r_pri == 0 -> gl = smu/s); element reciprocals
    if (t < 40) {
#pragma unroll
      for (int q = 0; q < NQ; ++q) {
        rs1[q] = drcp(s1[q]);
        glrc[q][t] = smu[q] * rs1[q];
        invd[q] = s1[q] * drcp(l1[q]);     // 1/d = s/lam
      }
    }
#pragma unroll
    for (int q = 0; q < NQ; ++q) {
#pragma unroll
      for (int j = 0; j < 7; ++j) {
        int i = t + 64 * j;
        if (i < N2) srs[q][j] = drcp(zr[q][j]);   // 1/s_slack (s==z)
      }
    }
    FENCE();

    // ---- D: phi = z/(eps*z+lam), y1 = rhs_z; store row-major + transposed tiles
#pragma unroll
    for (int q = 0; q < NQ; ++q) {
#pragma unroll
      for (int j = 0; j < 7; ++j) {
        int i = t + 64 * j;
        if (i < N2) {
          int r = rr_[j], c = cc_[j];
          double ph = zr[q][j] * drcp(fma(EPSd, zr[q][j], sl[q][j]));
          double y = -(EPSd * zr[q][j] + pr[q][j] + nu[q] * fair_d(c)
                       + glrc[q][r] + glrc[q][NN + c] - smu[q] * srs[q][j]);
          phim[q][r * ST + c] = ph;
          phimT[q][c * ST + r] = ph;
          y1m[q][r * ST + c] = y;
          y1T[q][c * ST + r] = y;
        }
      }
    }
    FENCE();

    // ---- E: fused row (0..19) / col (20..39) reductions, contiguous double2 reads
    if (t < 40) {
      const bool isrow = (t < NN);
      const int rc = isrow ? t : (t - NN);
#pragma unroll
      for (int q = 0; q < NQ; ++q) {
        const double2* pb = reinterpret_cast<const double2*>(isrow ? &phim[q][rc * ST] : &phimT[q][rc * ST]);
        const double2* yb = reinterpret_cast<const double2*>(isrow ? &y1m[q][rc * ST] : &y1T[q][rc * ST]);
        double a0A = 0.0, a0B = 0.0, a1A = 0.0, a1B = 0.0, a2A = 0.0, a2B = 0.0;
#pragma unroll
        for (int jj = 0; jj < 10; ++jj) {
          double2 ph = pb[jj];
          double2 yy = yb[jj];
          a0A += ph.x;                 a0B += ph.y;
          a1A = fma(ph.x, yy.x, a1A);  a1B = fma(ph.y, yy.y, a1B);
          a2A = fma(ph.x, fair_d(2 * jj), a2A);
          a2B = fma(ph.y, fair_d(2 * jj + 1), a2B);
        }
        e0[q] = a0A + a0B; e1[q] = a1A + a1B; e2[q] = a2A + a2B;
        if (isrow) {
          D1iloc[q] = drcp(invd[q] + e0[q]);
          D1iv[q][t] = D1iloc[q]; p1v[q][t] = e1[q]; p2v[q][t] = e2[q];
        } else {
          D2vv[q][rc] = invd[q] + e0[q];
          t1v[q][rc] = e1[q]; Ccv[q][rc] = e0[q];
        }
      }
    }
    FENCE();

    // ---- F: phiDT = (phi * D1i[row])^T  (phi re-read from LDS)
#pragma unroll
    for (int q = 0; q < NQ; ++q) {
#pragma unroll
      for (int j = 0; j < 7; ++j) {
        int i = t + 64 * j;
        if (i < N2) {
          int r = rr_[j], c = cc_[j];
          phiDT[q][c * ST + r] = phim[q][r * ST + c] * D1iv[q][r];
        }
      }
    }
    FENCE();

    // ---- G: Schur S = D2 - Phi^T D1^-1 Phi (all 400), rb1/rb2, a1G/a2G
#pragma unroll
    for (int q = 0; q < NQ; ++q) {
#pragma unroll
      for (int j = 0; j < 7; ++j) {
        int e = t + 64 * j;
        if (e < N2) {
          int c = e / NN, cp = e - (e / NN) * NN;
          const double2* pa = reinterpret_cast<const double2*>(&phiDT[q][c * ST]);
          const double2* pbb = reinterpret_cast<const double2*>(&phimT[q][cp * ST]);
          double accA = 0.0, accB = 0.0;
#pragma unroll
          for (int r = 0; r < 10; ++r) {
            double2 u = pa[r], v = pbb[r];
            accA = fma(u.x, v.x, accA);
            accB = fma(u.y, v.y, accB);
          }
          double Sv = -(accA + accB);
          if (c == cp) Sv += D2vv[q][c];
          SmX[q][c * ST + cp] = Sv;
        }
      }
    }
    if (t < NN) {
#pragma unroll
      for (int q = 0; q < NQ; ++q) {
        const double2* pa = reinterpret_cast<const double2*>(&phiDT[q][t * ST]);
        const double2* q1 = reinterpret_cast<const double2*>(p1v[q]);
        const double2* q2 = reinterpret_cast<const double2*>(p2v[q]);
        double a1A = 0.0, a1B = 0.0, a2A = 0.0, a2B = 0.0;
#pragma unroll
        for (int r = 0; r < 10; ++r) {
          double2 u = pa[r];
          double2 w1 = q1[r], w2 = q2[r];
          a1A = fma(u.x, w1.x, a1A); a1B = fma(u.y, w1.y, a1B);
          a2A = fma(u.x, w2.x, a2A); a2B = fma(u.y, w2.y, a2B);
        }
        double g1 = a1A + a1B, g2 = a2A + a2B;
        a1G[q][t] = g1; a2G[q][t] = g2;
        SmX[q][t * ST + NN] = t1v[q][t] - g1;                  // rb1
        SmX[q][t * ST + NN + 1] = fair_d(t) * Ccv[q][t] - g2;  // rb2
      }
    }
    FENCE();

    // ---- H: two interleaved Gauss-Jordans (independent rcp chains overlap)
    {
      double BA[NN], BB[NN];
#pragma unroll
      for (int i = 0; i < NN; ++i) {
        BA[i] = (t < NN + 2) ? SmX[0][i * ST + t] : 0.0;
        BB[i] = (t < NN + 2) ? SmX[1][i * ST + t] : 0.0;
      }
      double dinvA = drcp(dreadlane(BA[0], 0));
      double dinvB = drcp(dreadlane(BB[0], 0));
#pragma unroll
      for (int k = 0; k < NN; ++k) {
        double rkA = BA[k] * dinvA;
        double rkB = BB[k] * dinvB;
        if (k < NN - 1) {
          double cA = dreadlane(BA[k + 1], k);
          BA[k + 1] = fma(-cA, rkA, BA[k + 1]);
          double cB = dreadlane(BB[k + 1], k);
          BB[k + 1] = fma(-cB, rkB, BB[k + 1]);
          dinvA = drcp(dreadlane(BA[k + 1], k + 1));   // latency hidden below
          dinvB = drcp(dreadlane(BB[k + 1], k + 1));
        }
#pragma unroll
        for (int i = 0; i < NN; ++i) {
          if (i != k && !(k < NN - 1 && i == k + 1)) {
            double cA = dreadlane(BA[i], k);
            BA[i] = fma(-cA, rkA, BA[i]);
            double cB = dreadlane(BB[i], k);
            BB[i] = fma(-cB, rkB, BB[i]);
          }
        }
        BA[k] = rkA; BB[k] = rkB;
      }
      if (t == NN) {
#pragma unroll
        for (int i = 0; i < NN; ++i) { be1v[0][i] = BA[i]; be1v[1][i] = BB[i]; }
      }
      if (t == NN + 1) {
#pragma unroll
        for (int i = 0; i < NN; ++i) { be2v[0][i] = BA[i]; be2v[1][i] = BB[i]; }
      }
    }
    FENCE();

    // ---- I: row-lane pieces: PB, a_row, row W
    if (t < NN) {
#pragma unroll
      for (int q = 0; q < NQ; ++q) {
        const double2* pa = reinterpret_cast<const double2*>(&phim[q][t * ST]);
        const double2* q1 = reinterpret_cast<const double2*>(be1v[q]);
        const double2* q2 = reinterpret_cast<const double2*>(be2v[q]);
        double b1A = 0.0, b1B = 0.0, b2A = 0.0, b2B = 0.0;
#pragma unroll
        for (int c = 0; c < 10; ++c) {
          double2 ph = pa[c];
          double2 w1 = q1[c], w2 = q2[c];
          b1A = fma(ph.x, w1.x, b1A); b1B = fma(ph.y, w1.y, b1B);
          b2A = fma(ph.x, w2.x, b2A); b2B = fma(ph.y, w2.y, b2B);
        }
        double PB1 = b1A + b1B, PB2 = b2A + b2B;
        double a1r = (e1[q] - PB1) * D1iloc[q];
        double a2r = (e2[q] - PB2) * D1iloc[q];
        a1rv[q][t] = a1r; a2rv[q][t] = a2r;
        PB1v[q][t] = PB1; PB2v[q][t] = PB2;
        W1[q] = e1[q] - e0[q] * a1r - PB1;
        W2[q] = e2[q] - e0[q] * a2r - PB2;
      }
    }
    FENCE();

    // ---- J: element dots (phi,y1 re-read from LDS); col-lane W; fused wsum; dnu
    double l1d[NQ] = {0.0, 0.0}, l2d[NQ] = {0.0, 0.0};
#pragma unroll
    for (int q = 0; q < NQ; ++q) {
#pragma unroll
      for (int j = 0; j < 7; ++j) {
        int i = t + 64 * j;
        if (i < N2) {
          int r = rr_[j], c = cc_[j];
          double fc = fair_d(c);
          double ph = phim[q][r * ST + c];
          double yv = y1m[q][r * ST + c];
          double w1 = ph * (yv - a1rv[q][r] - be1v[q][c]);
          double w2 = ph * (fc - a2rv[q][r] - be2v[q][c]);
          du1[q][j] = w1; du2[q][j] = w2;
          l1d[q] = fma(fc, w1, l1d[q]);
          l2d[q] = fma(fc, w2, l2d[q]);
        }
      }
    }
    if (t >= NN && t < 2 * NN) {
      int c = t - NN;
#pragma unroll
      for (int q = 0; q < NQ; ++q) {
        const double2* pa = reinterpret_cast<const double2*>(&phiDT[q][c * ST]);
        const double2* q1 = reinterpret_cast<const double2*>(PB1v[q]);
        const double2* q2 = reinterpret_cast<const double2*>(PB2v[q]);
        double c1A = 0.0, c1B = 0.0, c2A = 0.0, c2B = 0.0;
#pragma unroll
        for (int r = 0; r < 10; ++r) {
          double2 u = pa[r];
          double2 w1 = q1[r], w2 = q2[r];
          c1A = fma(u.x, w1.x, c1A); c1B = fma(u.y, w1.y, c1B);
          c2A = fma(u.x, w2.x, c2A); c2B = fma(u.y, w2.y, c2B);
        }
        double A1 = a1G[q][c] - (c1A + c1B);
        double A2 = a2G[q][c] - (c2A + c2B);
        W1[q] = e1[q] - A1 - e0[q] * be1v[q][c];
        W2[q] = e0[q] * fair_d(c) - A2 - e0[q] * be2v[q][c];
      }
    }
#pragma unroll
    for (int off = 32; off > 0; off >>= 1) {
      l1d[0] += __shfl_xor(l1d[0], off, 64);
      l1d[1] += __shfl_xor(l1d[1], off, 64);
      l2d[0] += __shfl_xor(l2d[0], off, 64);
      l2d[1] += __shfl_xor(l2d[1], off, 64);
    }
    double dnu[NQ];
#pragma unroll
    for (int q = 0; q < NQ; ++q) {
      dnu[q] = (l1d[q] + req[q]) * drcp(l2d[q]);
      if (t < 40) sumdz[q] = W1[q] - dnu[q] * W2[q];
    }

    // ---- M: dz, dlam, step length, mu-recurrence terms; one fused reduction
    double lmin[NQ] = {1e30, 1e30}, T1[NQ] = {0.0, 0.0}, T2[NQ] = {0.0, 0.0};
    if (t < 40) {
#pragma unroll
      for (int q = 0; q < NQ; ++q) {
        ds1[q] = -sumdz[q];                            // r_pri == 0
        dl1[q] = (smu[q] - s1[q] * l1[q] - l1[q] * ds1[q]) * rs1[q];
        if (ds1[q] < 0.0) lmin[q] = fmin(lmin[q], -s1[q] * drcp(ds1[q]));
        if (dl1[q] < 0.0) lmin[q] = fmin(lmin[q], -l1[q] * drcp(dl1[q]));
        T1[q] = s1[q] * dl1[q] + l1[q] * ds1[q];
        T2[q] = ds1[q] * dl1[q];
      }
    }
#pragma unroll
    for (int q = 0; q < NQ; ++q) {
#pragma unroll
      for (int j = 0; j < 7; ++j) {
        int i = t + 64 * j;
        if (i < N2) {
          double dz = du1[q][j] - dnu[q] * du2[q][j];
          dzr[q][j] = dz;                               // ds_slack == dz
          double dl = (smu[q] - zr[q][j] * sl[q][j] - sl[q][j] * dz) * srs[q][j];
          sdl[q][j] = dl;
          if (dz < 0.0) lmin[q] = fmin(lmin[q], -zr[q][j] * drcp(dz));
          if (dl < 0.0) lmin[q] = fmin(lmin[q], -sl[q][j] * drcp(dl));
          T1[q] += zr[q][j] * dl + sl[q][j] * dz;
          T2[q] += dz * dl;
        }
      }
    }
#pragma unroll
    for (int off = 32; off > 0; off >>= 1) {
      lmin[0] = fmin(lmin[0], __shfl_xor(lmin[0], off, 64));
      lmin[1] = fmin(lmin[1], __shfl_xor(lmin[1], off, 64));
      T1[0] += __shfl_xor(T1[0], off, 64);
      T1[1] += __shfl_xor(T1[1], off, 64);
      T2[0] += __shfl_xor(T2[0], off, 64);
      T2[1] += __shfl_xor(T2[1], off, 64);
    }

    // ---- N: updates + exact recurrences (mu, req)
#pragma unroll
    for (int q = 0; q < NQ; ++q) {
      const double alpha = fmin(1.0, 0.99 * lmin[q]);
#pragma unroll
      for (int j = 0; j < 7; ++j) {
        int i = t + 64 * j;
        if (i < N2) {
          zr[q][j] = fma(alpha, dzr[q][j], zr[q][j]);
          sl[q][j] = fma(alpha, sdl[q][j], sl[q][j]);
        }
      }
      if (t < 40) {
        s1[q] = fma(alpha, ds1[q], s1[q]);
        l1[q] = fma(alpha, dl1[q], l1[q]);
      }
      nu[q] = fma(alpha, dnu[q], nu[q]);
      req[q] *= (1.0 - alpha);
      musum[q] = fma(alpha * alpha, T2[q], fma(alpha, T1[q], musum[q]));
      smu[q] = SIG * musum[q] * (1.0 / MM);
    }
    FENCE();
  }

#pragma unroll
  for (int q = 0; q < NQ; ++q) {
#pragma unroll
    for (int j = 0; j < 7; ++j) {
      int i = t + 64 * j;
      if (i < N2) out[(2 * b + q) * N2 + i] = (float)zr[q][j];
    }
  }
}

extern "C" void kernel_launch(void* const* d_in, const int* in_sizes, int n_in,
                              void* d_out, int out_size, void* d_ws, size_t ws_size,
                              hipStream_t stream) {
  const float* x = (const float*)d_in[0];
  float* out = (float*)d_out;
  hipLaunchKernelGGL(ipm_kernel, dim3(16), dim3(64), 0, stream, x, out);
}

// Round 8
// 312.424 us; speedup vs baseline: 2.2369x; 2.2369x over previous
//
#include <hip/hip_runtime.h>

#define NN 20
#define ST 22          // stride for 20-row fp64 tiles; rows 16B-aligned (b128-friendly)
#define N2 400
#define MM 440
#define NITERS 25

// single-wave block + per-wave in-order LDS pipeline => compiler fence suffices
#define FENCE() asm volatile("" ::: "memory")

__device__ __forceinline__ double drcp(double x) {
  double r = __builtin_amdgcn_rcp(x);       // v_rcp_f64 seed (may be f16-grade)
  r = fma(r, fma(-x, r, 1.0), r);           // NR 1
  r = fma(r, fma(-x, r, 1.0), r);           // NR 2 -> ~1 ulp (1-NR was R5's failure)
  return r;
}
__device__ __forceinline__ double dreadlane(double v, int lane) {
  int lo = __builtin_amdgcn_readlane(__double2loint(v), lane);
  int hi = __builtin_amdgcn_readlane(__double2hiint(v), lane);
  return __hiloint2double(hi, lo);
}
__device__ __forceinline__ double wsumd(double v) {
#pragma unroll
  for (int off = 32; off > 0; off >>= 1) v += __shfl_xor(v, off, 64);
  return v;
}
__device__ __forceinline__ double fair_d(int c) {
  return (c < 8) ? 0.125 : (double)(-1.0f / 12.0f);  // matches fp32 ref constant
}

__global__ __launch_bounds__(64, 1) void ipm_kernel(const float* __restrict__ x,
                                                    float* __restrict__ out) {
  const int b = blockIdx.x;
  const int t = threadIdx.x;

  __shared__ __align__(16) double phim[NN * ST];   // phi row-major
  __shared__ __align__(16) double phimT[NN * ST];  // phi transposed
  __shared__ __align__(16) double y1m[NN * ST];
  __shared__ __align__(16) double y1T[NN * ST];
  __shared__ __align__(16) double phiDT[NN * ST];  // (phi * D1i[row])^T
  __shared__ __align__(16) double SmX[NN * ST];    // row c: [S[c][0..19] | rb1 rb2]
  __shared__ __align__(16) double D2vv[NN], p1v[NN], p2v[NN];
  __shared__ __align__(16) double a1G[NN], a2G[NN];
  __shared__ __align__(16) double be1v[NN], be2v[NN];
  __shared__ __align__(16) double a1rv[NN], a2rv[NN], PB1v[NN], PB2v[NN];

  const double EPSd = 1e-4, SIG = 0.1;

  // element state: element i = t + 64*j; s_slack == z exactly (identical updates)
  double zr[7], pr[7], sl[7];
  double srs[7], phir[7], y1r[7], du1[7], du2[7], dzr[7], sdl[7];
  int rr_[7], cc_[7];
  // row/col constraint state on lanes t<40 (rows 0..19, cols 20..39); r_pri == 0
  double s1 = 0.5, l1 = 1.0, rs1 = 0.0, ds1 = 0.0, dl1 = 0.0, invd = 0.0, gl1 = 0.0;
  double e0 = 0.0, e1 = 0.0, e2 = 0.0, D1iloc = 0.0;
  double W1 = 0.0, W2 = 0.0, sumdz = 0.0;

  // 2x2 Schur block decode (triangular, 55 blocks), once per kernel
  int bc_ = 0;
  {
    int bid = t;
#pragma unroll
    for (int q = 0; q < 9; ++q) {
      if (bc_ < 9 && bid >= 10 - bc_) { bid -= 10 - bc_; ++bc_; }
    }
    bc_ = (t < 55) ? bc_ : 0;
    // bp_ recomputed below from bid; store both
    rr_[0] = 0;  // placeholder to silence unused warnings (overwritten)
  }
  int bp_;
  {
    int bid = t, c = 0;
#pragma unroll
    for (int q = 0; q < 9; ++q) {
      if (c < 9 && bid >= 10 - c) { bid -= 10 - c; ++c; }
    }
    bp_ = (t < 55) ? (c + bid) : 0;
    bc_ = (t < 55) ? c : 0;
  }

  double lreq0 = 0.0;
#pragma unroll
  for (int j = 0; j < 7; ++j) {
    int i = t + 64 * j;
    if (i < N2) {
      int r = i / NN, c = i - (i / NN) * NN;
      rr_[j] = r; cc_[j] = c;
      zr[j] = 0.025;
      pr[j] = -(double)x[b * N2 + i];
      sl[j] = 1.0;
      lreq0 += fair_d(c) * 0.025;
    } else { rr_[j] = 0; cc_[j] = 0; zr[j] = 0.025; pr[j] = 0.0; sl[j] = 1.0; }
  }
  double req = wsumd(lreq0);
  double nu = 0.0;
  double musum = 30.0;                 // exact: 40*0.5 + 400*0.025
  double smu = SIG * musum * (1.0 / MM);

#pragma unroll 1
  for (int it = 0; it < NITERS; ++it) {
    // ---- C: per-constraint scalars (r_pri == 0 -> gl = smu/s); element recips
    {
      double s1c = (t < 40) ? s1 : 1.0;
      double l1c = (t < 40) ? l1 : 1.0;
      rs1 = drcp(s1c);
      gl1 = smu * rs1;                 // valid on lanes <40; others harmless
      invd = s1c * drcp(l1c);
    }
#pragma unroll
    for (int j = 0; j < 7; ++j) {
      srs[j] = drcp(zr[j]);                              // 1/s_slack (s==z)
      phir[j] = zr[j] * drcp(fma(EPSd, zr[j], sl[j]));   // 1/(EPS + lam/s)
    }

    // ---- D: y1 = rhs_z; gl broadcast by shfl at FULL exec mask; store tiles
#pragma unroll
    for (int j = 0; j < 7; ++j) {
      int r = rr_[j], c = cc_[j];
      double glr = __shfl(gl1, r);          // all 64 lanes execute
      double glc = __shfl(gl1, NN + c);
      int i = t + 64 * j;
      if (i < N2) {
        double y = -(EPSd * zr[j] + pr[j] + nu * fair_d(c)
                     + glr + glc - smu * srs[j]);
        y1r[j] = y;
        phim[r * ST + c] = phir[j];
        phimT[c * ST + r] = phir[j];
        y1m[r * ST + c] = y;
        y1T[c * ST + r] = y;
      }
    }
    FENCE();

    // ---- E: fused row (0..19) / col (20..39) reductions, contiguous double2
    if (t < 40) {
      const bool isrow = (t < NN);
      const int rc = isrow ? t : (t - NN);
      const double2* pb = reinterpret_cast<const double2*>(isrow ? &phim[rc * ST] : &phimT[rc * ST]);
      const double2* yb = reinterpret_cast<const double2*>(isrow ? &y1m[rc * ST] : &y1T[rc * ST]);
      double a0A = 0.0, a0B = 0.0, a1A = 0.0, a1B = 0.0, a2A = 0.0, a2B = 0.0;
#pragma unroll
      for (int jj = 0; jj < 10; ++jj) {
        double2 ph = pb[jj];
        double2 yy = yb[jj];
        a0A += ph.x;                 a0B += ph.y;
        a1A = fma(ph.x, yy.x, a1A);  a1B = fma(ph.y, yy.y, a1B);
        a2A = fma(ph.x, fair_d(2 * jj), a2A);
        a2B = fma(ph.y, fair_d(2 * jj + 1), a2B);
      }
      e0 = a0A + a0B; e1 = a1A + a1B; e2 = a2A + a2B;
      if (isrow) {
        D1iloc = drcp(invd + e0);
        p1v[t] = e1; p2v[t] = e2;
      } else {
        D2vv[rc] = invd + e0;
      }
    }
    FENCE();

    // ---- F: phiDT = (phi * D1i[row])^T  (D1i broadcast by shfl, full mask)
#pragma unroll
    for (int j = 0; j < 7; ++j) {
      double d1r = __shfl(D1iloc, rr_[j]);  // all lanes execute
      int i = t + 64 * j;
      if (i < N2) phiDT[cc_[j] * ST + rr_[j]] = phir[j] * d1r;
    }
    FENCE();

    // ---- G: Schur via 2x2 triangular blocks (55 blocks, 1/lane) + rb rows
    {
      // shfl of col-lane reductions at full mask (for rb on row lanes)
      int cidx = NN + (t % NN);
      double t1c = __shfl(e1, cidx);
      double Ccl = __shfl(e0, cidx);
      if (t < 55) {
        const int c0 = 2 * bc_, c1i = 2 * bc_ + 1, q0 = 2 * bp_, q1i = 2 * bp_ + 1;
        const double2* pa0 = reinterpret_cast<const double2*>(&phiDT[c0 * ST]);
        const double2* pa1 = reinterpret_cast<const double2*>(&phiDT[c1i * ST]);
        const double2* pb0 = reinterpret_cast<const double2*>(&phimT[q0 * ST]);
        const double2* pb1 = reinterpret_cast<const double2*>(&phimT[q1i * ST]);
        double s00A = 0, s00B = 0, s01A = 0, s01B = 0;
        double s10A = 0, s10B = 0, s11A = 0, s11B = 0;
#pragma unroll
        for (int r = 0; r < 10; ++r) {
          double2 a0 = pa0[r], a1 = pa1[r], b0 = pb0[r], b1 = pb1[r];
          s00A = fma(a0.x, b0.x, s00A); s00B = fma(a0.y, b0.y, s00B);
          s01A = fma(a0.x, b1.x, s01A); s01B = fma(a0.y, b1.y, s01B);
          s10A = fma(a1.x, b0.x, s10A); s10B = fma(a1.y, b0.y, s10B);
          s11A = fma(a1.x, b1.x, s11A); s11B = fma(a1.y, b1.y, s11B);
        }
        double S00 = -(s00A + s00B), S01 = -(s01A + s01B);
        double S10 = -(s10A + s10B), S11 = -(s11A + s11B);
        if (bc_ == bp_) { S00 += D2vv[c0]; S11 += D2vv[c1i]; }
        SmX[c0 * ST + q0] = S00;  SmX[c0 * ST + q1i] = S01;
        SmX[c1i * ST + q0] = S10; SmX[c1i * ST + q1i] = S11;
        if (bc_ != bp_) {  // mirrors are bit-exact (same products, same order)
          SmX[q0 * ST + c0] = S00;  SmX[q1i * ST + c0] = S01;
          SmX[q0 * ST + c1i] = S10; SmX[q1i * ST + c1i] = S11;
        }
      }
      if (t < NN) {
        const double2* pa = reinterpret_cast<const double2*>(&phiDT[t * ST]);
        const double2* q1 = reinterpret_cast<const double2*>(p1v);
        const double2* q2 = reinterpret_cast<const double2*>(p2v);
        double a1A = 0.0, a1B = 0.0, a2A = 0.0, a2B = 0.0;
#pragma unroll
        for (int r = 0; r < 10; ++r) {
          double2 u = pa[r];
          double2 w1 = q1[r], w2 = q2[r];
          a1A = fma(u.x, w1.x, a1A); a1B = fma(u.y, w1.y, a1B);
          a2A = fma(u.x, w2.x, a2A); a2B = fma(u.y, w2.y, a2B);
        }
        double g1 = a1A + a1B, g2 = a2A + a2B;
        a1G[t] = g1; a2G[t] = g2;
        SmX[t * ST + NN] = t1c - g1;                 // rb1
        SmX[t * ST + NN + 1] = fair_d(t) * Ccl - g2; // rb2
      }
    }
    FENCE();

    // ---- H: Gauss-Jordan; lane t owns column t; pivot rcp software-pipelined
    {
      double B[NN];
#pragma unroll
      for (int i = 0; i < NN; ++i) B[i] = (t < NN + 2) ? SmX[i * ST + t] : 0.0;
      double dinv;
      { double piv = dreadlane(B[0], 0); dinv = drcp(piv); }
#pragma unroll
      for (int k = 0; k < NN; ++k) {
        double rk = B[k] * dinv;
        if (k < NN - 1) {
          double ck1 = dreadlane(B[k + 1], k);
          B[k + 1] = fma(-ck1, rk, B[k + 1]);
          double piv1 = dreadlane(B[k + 1], k + 1);
          dinv = drcp(piv1);                       // latency hidden below
        }
#pragma unroll
        for (int i = 0; i < NN; ++i) {
          if (i != k && !(k < NN - 1 && i == k + 1)) {
            double ck = dreadlane(B[i], k);        // pre-step column-k value
            B[i] = fma(-ck, rk, B[i]);
          }
        }
        B[k] = rk;
      }
      if (t == NN) {
#pragma unroll
        for (int i = 0; i < NN; ++i) be1v[i] = B[i];
      }
      if (t == NN + 1) {
#pragma unroll
        for (int i = 0; i < NN; ++i) be2v[i] = B[i];
      }
    }
    FENCE();

    // ---- I: row-lane pieces: PB, a_row, row W
    if (t < NN) {
      const double2* pa = reinterpret_cast<const double2*>(&phim[t * ST]);
      const double2* q1 = reinterpret_cast<const double2*>(be1v);
      const double2* q2 = reinterpret_cast<const double2*>(be2v);
      double b1A = 0.0, b1B = 0.0, b2A = 0.0, b2B = 0.0;
#pragma unroll
      for (int c = 0; c < 10; ++c) {
        double2 ph = pa[c];
        double2 w1 = q1[c], w2 = q2[c];
        b1A = fma(ph.x, w1.x, b1A); b1B = fma(ph.y, w1.y, b1B);
        b2A = fma(ph.x, w2.x, b2A); b2B = fma(ph.y, w2.y, b2B);
      }
      double PB1 = b1A + b1B, PB2 = b2A + b2B;
      double a1r = (e1 - PB1) * D1iloc;
      double a2r = (e2 - PB2) * D1iloc;
      a1rv[t] = a1r; a2rv[t] = a2r;
      PB1v[t] = PB1; PB2v[t] = PB2;
      W1 = e1 - e0 * a1r - PB1;
      W2 = e2 - e0 * a2r - PB2;
    }
    FENCE();

    // ---- J: w1/w2 per element; col-lane W; fused wsum; dnu
    double l1d = 0.0, l2d = 0.0;
#pragma unroll
    for (int j = 0; j < 7; ++j) {
      int i = t + 64 * j;
      if (i < N2) {
        int r = rr_[j], c = cc_[j];
        double fc = fair_d(c);
        double w1 = phir[j] * (y1r[j] - a1rv[r] - be1v[c]);
        double w2 = phir[j] * (fc - a2rv[r] - be2v[c]);
        du1[j] = w1; du2[j] = w2;
        l1d = fma(fc, w1, l1d);
        l2d = fma(fc, w2, l2d);
      }
    }
    if (t >= NN && t < 2 * NN) {
      int c = t - NN;
      const double2* pa = reinterpret_cast<const double2*>(&phiDT[c * ST]);
      const double2* q1 = reinterpret_cast<const double2*>(PB1v);
      const double2* q2 = reinterpret_cast<const double2*>(PB2v);
      double c1A = 0.0, c1B = 0.0, c2A = 0.0, c2B = 0.0;
#pragma unroll
      for (int r = 0; r < 10; ++r) {
        double2 u = pa[r];
        double2 w1 = q1[r], w2 = q2[r];
        c1A = fma(u.x, w1.x, c1A); c1B = fma(u.y, w1.y, c1B);
        c2A = fma(u.x, w2.x, c2A); c2B = fma(u.y, w2.y, c2B);
      }
      double A1 = a1G[c] - (c1A + c1B);
      double A2 = a2G[c] - (c2A + c2B);
      W1 = e1 - A1 - e0 * be1v[c];
      W2 = e0 * fair_d(c) - A2 - e0 * be2v[c];
    }
#pragma unroll
    for (int off = 32; off > 0; off >>= 1) {
      l1d += __shfl_xor(l1d, off, 64);
      l2d += __shfl_xor(l2d, off, 64);
    }
    const double dnu = (l1d + req) * drcp(l2d);
    if (t < 40) sumdz = W1 - dnu * W2;

    // ---- M: dz, dlam, step length, mu-recurrence terms; one fused reduction
    double lmin = 1e30, T1 = 0.0, T2 = 0.0;
    if (t < 40) {
      ds1 = -sumdz;                            // r_pri == 0
      dl1 = (smu - s1 * l1 - l1 * ds1) * rs1;
      if (ds1 < 0.0) lmin = fmin(lmin, -s1 * drcp(ds1));
      if (dl1 < 0.0) lmin = fmin(lmin, -l1 * drcp(dl1));
      T1 = s1 * dl1 + l1 * ds1;
      T2 = ds1 * dl1;
    }
#pragma unroll
    for (int j = 0; j < 7; ++j) {
      int i = t + 64 * j;
      if (i < N2) {
        double dz = du1[j] - dnu * du2[j];
        dzr[j] = dz;                           // ds_slack == dz
        double dl = (smu - zr[j] * sl[j] - sl[j] * dz) * srs[j];
        sdl[j] = dl;
        if (dz < 0.0) lmin = fmin(lmin, -zr[j] * drcp(dz));
        if (dl < 0.0) lmin = fmin(lmin, -sl[j] * drcp(dl));
        T1 += zr[j] * dl + sl[j] * dz;
        T2 += dz * dl;
      }
    }
#pragma unroll
    for (int off = 32; off > 0; off >>= 1) {
      lmin = fmin(lmin, __shfl_xor(lmin, off, 64));
      T1 += __shfl_xor(T1, off, 64);
      T2 += __shfl_xor(T2, off, 64);
    }
    const double alpha = fmin(1.0, 0.99 * lmin);

    // ---- N: updates + exact recurrences (mu, req)
#pragma unroll
    for (int j = 0; j < 7; ++j) {
      int i = t + 64 * j;
      if (i < N2) {
        zr[j] = fma(alpha, dzr[j], zr[j]);
        sl[j] = fma(alpha, sdl[j], sl[j]);
      }
    }
    if (t < 40) {
      s1 = fma(alpha, ds1, s1);
      l1 = fma(alpha, dl1, l1);
    }
    nu = fma(alpha, dnu, nu);
    req *= (1.0 - alpha);
    musum = fma(alpha * alpha, T2, fma(alpha, T1, musum));
    smu = SIG * musum * (1.0 / MM);
    FENCE();
  }

#pragma unroll
  for (int j = 0; j < 7; ++j) {
    int i = t + 64 * j;
    if (i < N2) out[b * N2 + i] = (float)zr[j];
  }
}

extern "C" void kernel_launch(void* const* d_in, const int* in_sizes, int n_in,
                              void* d_out, int out_size, void* d_ws, size_t ws_size,
                              hipStream_t stream) {
  const float* x = (const float*)d_in[0];
  float* out = (float*)d_out;
  hipLaunchKernelGGL(ipm_kernel, dim3(32), dim3(64), 0, stream, x, out);
}

// Round 9
// 283.960 us; speedup vs baseline: 2.4611x; 1.1002x over previous
//
#include <hip/hip_runtime.h>

#define NN 20
#define ST 22          // stride for 20-row fp64 tiles; rows 16B-aligned (b128-friendly)
#define N2 400
#define MM 440
#define NITERS 25

// single-wave block + per-wave in-order LDS pipeline => compiler fence suffices
#define FENCE() asm volatile("" ::: "memory")

__device__ __forceinline__ double drcp(double x) {
  double r = __builtin_amdgcn_rcp(x);       // v_rcp_f64 seed (may be f16-grade)
  r = fma(r, fma(-x, r, 1.0), r);           // NR 1
  r = fma(r, fma(-x, r, 1.0), r);           // NR 2 -> ~1 ulp (1-NR was R5's failure)
  return r;
}
__device__ __forceinline__ double dreadlane(double v, int lane) {
  int lo = __builtin_amdgcn_readlane(__double2loint(v), lane);
  int hi = __builtin_amdgcn_readlane(__double2hiint(v), lane);
  return __hiloint2double(hi, lo);
}
__device__ __forceinline__ double wsumd(double v) {
#pragma unroll
  for (int off = 32; off > 0; off >>= 1) v += __shfl_xor(v, off, 64);
  return v;
}
__device__ __forceinline__ double fair_d(int c) {
  return (c < 8) ? 0.125 : (double)(-1.0f / 12.0f);  // matches fp32 ref constant
}

__global__ __launch_bounds__(64, 1) void ipm_kernel(const float* __restrict__ x,
                                                    float* __restrict__ out) {
  const int b = blockIdx.x;
  const int t = threadIdx.x;

  __shared__ __align__(16) double phim[NN * ST];   // phi row-major
  __shared__ __align__(16) double phimT[NN * ST];  // phi transposed
  __shared__ __align__(16) double y1m[NN * ST];
  __shared__ __align__(16) double y1T[NN * ST];
  __shared__ __align__(16) double phiDT[NN * ST];  // (phi * D1i[row])^T
  __shared__ __align__(16) double SmX[ST * ST];    // rows 0..19: S (full, symmetric); rows 20/21: rb1/rb2
  __shared__ __align__(16) double D2vv[NN], p1v[NN], p2v[NN];
  __shared__ __align__(16) double bev[2 * NN];     // interleaved (be1[c], be2[c])

  const double EPSd = 1e-4, SIG = 0.1;

  // element state: element i = t + 64*j; s_slack == z exactly (identical updates)
  double zr[7], sl[7];
  double srs[7], rl[7], phir[7], y1r[7], du1[7], du2[7], dzr[7], sdl[7];
  int rr_[7], cc_[7];
  // row/col constraint state on lanes t<40 (rows 0..19, cols 20..39); r_pri == 0
  double s1 = 0.5, l1 = 1.0, rs1 = 0.0, ds1 = 0.0, dl1 = 0.0, invd = 0.0, gl1 = 0.0;
  double e0 = 0.0, e1 = 0.0, e2 = 0.0, D1iloc = 0.0;
  double W1 = 0.0, W2 = 0.0, sumdz = 0.0;

  // 2x2 Schur block decode (triangular, 55 blocks), once per kernel [R8-verified]
  int bc_, bp_;
  {
    int bid = t, c = 0;
#pragma unroll
    for (int q = 0; q < 9; ++q) {
      if (c < 9 && bid >= 10 - c) { bid -= 10 - c; ++c; }
    }
    bp_ = (t < 55) ? (c + bid) : 0;
    bc_ = (t < 55) ? c : 0;
  }

  double lreq0 = 0.0;
#pragma unroll
  for (int j = 0; j < 7; ++j) {
    int i = t + 64 * j;
    if (i < N2) {
      int r = i / NN, c = i - (i / NN) * NN;
      rr_[j] = r; cc_[j] = c;
      zr[j] = 0.025;
      sl[j] = 1.0;
      lreq0 += fair_d(c) * 0.025;
    } else { rr_[j] = 0; cc_[j] = 0; zr[j] = 0.025; sl[j] = 1.0; }
  }
  double req = wsumd(lreq0);
  double nu = 0.0;
  double musum = 30.0;                 // exact: 40*0.5 + 400*0.025
  double smu = SIG * musum * (1.0 / MM);

#pragma unroll 1
  for (int it = 0; it < NITERS; ++it) {
    // ---- C: prefetch p (L2-hot), per-constraint scalars, element recips
    float pf[7];
#pragma unroll
    for (int j = 0; j < 7; ++j) {
      int i = t + 64 * j;
      pf[j] = (i < N2) ? x[b * N2 + i] : 0.0f;
    }
    {
      double s1c = (t < 40) ? s1 : 1.0;
      double l1c = (t < 40) ? l1 : 1.0;
      rs1 = drcp(s1c);
      gl1 = smu * rs1;                 // valid on lanes <40
      invd = s1c * drcp(l1c);
    }
#pragma unroll
    for (int j = 0; j < 7; ++j) {
      srs[j] = drcp(zr[j]);                              // 1/s_slack (s==z)
      rl[j] = drcp(sl[j]);                               // 1/lam (for step ratios)
      phir[j] = zr[j] * drcp(fma(EPSd, zr[j], sl[j]));   // 1/(EPS + lam/s)
    }

    // ---- D: y1 = rhs_z; gl broadcast by shfl (full mask); store tiles
#pragma unroll
    for (int j = 0; j < 7; ++j) {
      int r = rr_[j], c = cc_[j];
      double glr = __shfl(gl1, r);
      double glc = __shfl(gl1, NN + c);
      int i = t + 64 * j;
      if (i < N2) {
        double pv = -(double)pf[j];
        double y = -(EPSd * zr[j] + pv + nu * fair_d(c)
                     + glr + glc - smu * srs[j]);
        y1r[j] = y;
        phim[r * ST + c] = phir[j];
        phimT[c * ST + r] = phir[j];
        y1m[r * ST + c] = y;
        y1T[c * ST + r] = y;
      }
    }
    FENCE();

    // ---- E: fused row (0..19) / col (20..39) reductions, contiguous double2
    if (t < 40) {
      const bool isrow = (t < NN);
      const int rc = isrow ? t : (t - NN);
      const double2* pb = reinterpret_cast<const double2*>(isrow ? &phim[rc * ST] : &phimT[rc * ST]);
      const double2* yb = reinterpret_cast<const double2*>(isrow ? &y1m[rc * ST] : &y1T[rc * ST]);
      double a0A = 0.0, a0B = 0.0, a1A = 0.0, a1B = 0.0, a2A = 0.0, a2B = 0.0;
#pragma unroll
      for (int jj = 0; jj < 10; ++jj) {
        double2 ph = pb[jj];
        double2 yy = yb[jj];
        a0A += ph.x;                 a0B += ph.y;
        a1A = fma(ph.x, yy.x, a1A);  a1B = fma(ph.y, yy.y, a1B);
        a2A = fma(ph.x, fair_d(2 * jj), a2A);
        a2B = fma(ph.y, fair_d(2 * jj + 1), a2B);
      }
      e0 = a0A + a0B; e1 = a1A + a1B; e2 = a2A + a2B;
      if (isrow) {
        D1iloc = drcp(invd + e0);
        p1v[t] = e1; p2v[t] = e2;
      } else {
        D2vv[rc] = invd + e0;
      }
    }
    FENCE();

    // ---- F: phiDT = (phi * D1i[row])^T  (D1i broadcast by shfl, full mask)
#pragma unroll
    for (int j = 0; j < 7; ++j) {
      double d1r = __shfl(D1iloc, rr_[j]);
      int i = t + 64 * j;
      if (i < N2) phiDT[cc_[j] * ST + rr_[j]] = phir[j] * d1r;
    }
    FENCE();

    // ---- G: Schur via 2x2 triangular blocks (55 lanes) + rb rows 20/21
    double g1loc = 0.0, g2loc = 0.0;
    {
      int cidx0 = NN + (t % NN);
      double t1c = __shfl(e1, cidx0);   // col-lane T1 for row lanes (full mask)
      double Ccl = __shfl(e0, cidx0);   // col-lane colsum(phi)
      if (t < 55) {
        const int c0 = 2 * bc_, c1i = 2 * bc_ + 1, q0 = 2 * bp_, q1i = 2 * bp_ + 1;
        const double2* pa0 = reinterpret_cast<const double2*>(&phiDT[c0 * ST]);
        const double2* pa1 = reinterpret_cast<const double2*>(&phiDT[c1i * ST]);
        const double2* pb0 = reinterpret_cast<const double2*>(&phimT[q0 * ST]);
        const double2* pb1 = reinterpret_cast<const double2*>(&phimT[q1i * ST]);
        double s00A = 0, s00B = 0, s01A = 0, s01B = 0;
        double s10A = 0, s10B = 0, s11A = 0, s11B = 0;
#pragma unroll
        for (int r = 0; r < 10; ++r) {
          double2 a0 = pa0[r], a1 = pa1[r], b0 = pb0[r], b1 = pb1[r];
          s00A = fma(a0.x, b0.x, s00A); s00B = fma(a0.y, b0.y, s00B);
          s01A = fma(a0.x, b1.x, s01A); s01B = fma(a0.y, b1.y, s01B);
          s10A = fma(a1.x, b0.x, s10A); s10B = fma(a1.y, b0.y, s10B);
          s11A = fma(a1.x, b1.x, s11A); s11B = fma(a1.y, b1.y, s11B);
        }
        double S00 = -(s00A + s00B), S01 = -(s01A + s01B);
        double S10 = -(s10A + s10B), S11 = -(s11A + s11B);
        if (bc_ == bp_) { S00 += D2vv[c0]; S11 += D2vv[c1i]; }
        SmX[c0 * ST + q0] = S00;  SmX[c0 * ST + q1i] = S01;
        SmX[c1i * ST + q0] = S10; SmX[c1i * ST + q1i] = S11;
        if (bc_ != bp_) {  // mirrors bit-exact (same products)
          SmX[q0 * ST + c0] = S00;  SmX[q1i * ST + c0] = S01;
          SmX[q0 * ST + c1i] = S10; SmX[q1i * ST + c1i] = S11;
        }
      }
      if (t < NN) {
        const double2* pa = reinterpret_cast<const double2*>(&phiDT[t * ST]);
        const double2* q1 = reinterpret_cast<const double2*>(p1v);
        const double2* q2 = reinterpret_cast<const double2*>(p2v);
        double a1A = 0.0, a1B = 0.0, a2A = 0.0, a2B = 0.0;
#pragma unroll
        for (int r = 0; r < 10; ++r) {
          double2 u = pa[r];
          double2 w1 = q1[r], w2 = q2[r];
          a1A = fma(u.x, w1.x, a1A); a1B = fma(u.y, w1.y, a1B);
          a2A = fma(u.x, w2.x, a2A); a2B = fma(u.y, w2.y, a2B);
        }
        g1loc = a1A + a1B; g2loc = a2A + a2B;
        SmX[20 * ST + t] = t1c - g1loc;                 // rb1 as row 20 (stride-1 write)
        SmX[21 * ST + t] = fair_d(t) * Ccl - g2loc;     // rb2 as row 21
      }
    }
    FENCE();

    // ---- H: Gauss-Jordan; lane t owns column t; loads = contiguous row t (S symmetric)
    {
      double B[NN];
      {
        int rowi = (t < NN + 2) ? t : 0;
        const double2* srcr = reinterpret_cast<const double2*>(&SmX[rowi * ST]);
#pragma unroll
        for (int k2 = 0; k2 < 10; ++k2) {
          double2 v = srcr[k2];
          B[2 * k2] = v.x; B[2 * k2 + 1] = v.y;
        }
      }
      double dinv;
      { double piv = dreadlane(B[0], 0); dinv = drcp(piv); }
#pragma unroll
      for (int k = 0; k < NN; ++k) {
        double rk = B[k] * dinv;
        if (k < NN - 1) {
          double ck1 = dreadlane(B[k + 1], k);
          B[k + 1] = fma(-ck1, rk, B[k + 1]);
          double piv1 = dreadlane(B[k + 1], k + 1);
          dinv = drcp(piv1);                       // latency hidden below
        }
#pragma unroll
        for (int i = 0; i < NN; ++i) {
          if (i != k && !(k < NN - 1 && i == k + 1)) {
            double ck = dreadlane(B[i], k);        // pre-step column-k value
            B[i] = fma(-ck, rk, B[i]);
          }
        }
        B[k] = rk;
      }
      if (t == NN || t == NN + 1) {                // interleaved (be1[c],be2[c]) pairs
        int off = t - NN;
#pragma unroll
        for (int i = 0; i < NN; ++i) bev[2 * i + off] = B[i];
      }
    }
    FENCE();

    // ---- I+J merged: row pieces -> col pieces -> element w -> dnu (readlane sum)
    double PB1 = 0.0, PB2 = 0.0, a1rloc = 0.0, a2rloc = 0.0;
    {
      int cidx = (t >= NN && t < 2 * NN) ? (t - NN) : 0;
      double g1c = __shfl(g1loc, cidx);            // a1G[c] for col lanes (full mask)
      double g2c = __shfl(g2loc, cidx);
      if (t < NN) {
        const double2* pa = reinterpret_cast<const double2*>(&phim[t * ST]);
        const double2* bv = reinterpret_cast<const double2*>(bev);
        double b1A = 0.0, b1B = 0.0, b2A = 0.0, b2B = 0.0;
#pragma unroll
        for (int c = 0; c < 10; ++c) {
          double2 ph = pa[c];
          double2 e0b = bv[2 * c];        // (be1[2c], be2[2c])
          double2 e1b = bv[2 * c + 1];    // (be1[2c+1], be2[2c+1])
          b1A = fma(ph.x, e0b.x, b1A); b2A = fma(ph.x, e0b.y, b2A);
          b1B = fma(ph.y, e1b.x, b1B); b2B = fma(ph.y, e1b.y, b2B);
        }
        PB1 = b1A + b1B; PB2 = b2A + b2B;
        a1rloc = (e1 - PB1) * D1iloc;
        a2rloc = (e2 - PB2) * D1iloc;
        W1 = e1 - e0 * a1rloc - PB1;
        W2 = e2 - e0 * a2rloc - PB2;
      }
      if (t >= NN && t < 2 * NN) {
        int c = t - NN;
        const double2* pa = reinterpret_cast<const double2*>(&phiDT[c * ST]);
        double c1A = 0.0, c1B = 0.0, c2A = 0.0, c2B = 0.0;
#pragma unroll
        for (int r = 0; r < 10; ++r) {
          double2 u = pa[r];
          double pb1x = dreadlane(PB1, 2 * r), pb1y = dreadlane(PB1, 2 * r + 1);
          double pb2x = dreadlane(PB2, 2 * r), pb2y = dreadlane(PB2, 2 * r + 1);
          c1A = fma(u.x, pb1x, c1A); c1B = fma(u.y, pb1y, c1B);
          c2A = fma(u.x, pb2x, c2A); c2B = fma(u.y, pb2y, c2B);
        }
        double A1 = g1c - (c1A + c1B);
        double A2 = g2c - (c2A + c2B);
        const double2* bv = reinterpret_cast<const double2*>(bev);
        double2 bec = bv[c];                       // (be1[c], be2[c])
        W1 = e1 - A1 - e0 * bec.x;                 // colsum(w1)
        W2 = e0 * fair_d(c) - A2 - e0 * bec.y;     // colsum(w2)
      }
    }
    // element w1/w2 (a_row via shfl, be via interleaved b128 read)
#pragma unroll
    for (int j = 0; j < 7; ++j) {
      double a1e = __shfl(a1rloc, rr_[j]);         // full mask
      double a2e = __shfl(a2rloc, rr_[j]);
      int i = t + 64 * j;
      if (i < N2) {
        const double2* bv = reinterpret_cast<const double2*>(bev);
        double2 bec = bv[cc_[j]];
        du1[j] = phir[j] * (y1r[j] - a1e - bec.x);
        du2[j] = phir[j] * (fair_d(cc_[j]) - a2e - bec.y);
      }
    }
    // dnu from col-lane colsums: l1 = sum_c fair[c]*W1[20+c] (exact reordering)
    double dnu;
    {
      double sA = 0.0, sB = 0.0, uA = 0.0, uB = 0.0;
#pragma unroll
      for (int c = 0; c < NN; c += 2) {
        sA = fma(fair_d(c),     dreadlane(W1, NN + c),     sA);
        sB = fma(fair_d(c + 1), dreadlane(W1, NN + c + 1), sB);
        uA = fma(fair_d(c),     dreadlane(W2, NN + c),     uA);
        uB = fma(fair_d(c + 1), dreadlane(W2, NN + c + 1), uB);
      }
      dnu = ((sA + sB) + req) * drcp(uA + uB);
    }
    if (t < 40) sumdz = W1 - dnu * W2;

    // ---- M: dz, dlam, branchless max-ratio (no per-candidate division), T1/T2
    double maxr = 0.0, T1 = 0.0, T2 = 0.0;
    if (t < 40) {
      ds1 = -sumdz;                              // r_pri == 0
      dl1 = (smu - s1 * l1 - l1 * ds1) * rs1;
      maxr = fmax(maxr, -ds1 * rs1);             // = max(-ds/s)
      maxr = fmax(maxr, -dl1 * (rs1 * invd));    // rs1*invd = 1/lam
      T1 = s1 * dl1 + l1 * ds1;
      T2 = ds1 * dl1;
    }
#pragma unroll
    for (int j = 0; j < 7; ++j) {
      int i = t + 64 * j;
      if (i < N2) {
        double dz = du1[j] - dnu * du2[j];
        dzr[j] = dz;                             // ds_slack == dz
        double dl = (smu - zr[j] * sl[j] - sl[j] * dz) * srs[j];
        sdl[j] = dl;
        maxr = fmax(maxr, -dz * srs[j]);
        maxr = fmax(maxr, -dl * rl[j]);
        T1 += zr[j] * dl + sl[j] * dz;
        T2 += dz * dl;
      }
    }
#pragma unroll
    for (int off = 32; off > 0; off >>= 1) {
      maxr = fmax(maxr, __shfl_xor(maxr, off, 64));
      T1 += __shfl_xor(T1, off, 64);
      T2 += __shfl_xor(T2, off, 64);
    }
    const double alpha = fmin(1.0, 0.99 * drcp(maxr));  // maxr==0 -> inf -> 1

    // ---- N: updates + exact recurrences (mu, req)
#pragma unroll
    for (int j = 0; j < 7; ++j) {
      int i = t + 64 * j;
      if (i < N2) {
        zr[j] = fma(alpha, dzr[j], zr[j]);
        sl[j] = fma(alpha, sdl[j], sl[j]);
      }
    }
    if (t < 40) {
      s1 = fma(alpha, ds1, s1);
      l1 = fma(alpha, dl1, l1);
    }
    nu = fma(alpha, dnu, nu);
    req *= (1.0 - alpha);
    musum = fma(alpha * alpha, T2, fma(alpha, T1, musum));
    smu = SIG * musum * (1.0 / MM);
    FENCE();
  }

#pragma unroll
  for (int j = 0; j < 7; ++j) {
    int i = t + 64 * j;
    if (i < N2) out[b * N2 + i] = (float)zr[j];
  }
}

extern "C" void kernel_launch(void* const* d_in, const int* in_sizes, int n_in,
                              void* d_out, int out_size, void* d_ws, size_t ws_size,
                              hipStream_t stream) {
  const float* x = (const float*)d_in[0];
  float* out = (float*)d_out;
  hipLaunchKernelGGL(ipm_kernel, dim3(32), dim3(64), 0, stream, x, out);
}

// Round 10
// 283.917 us; speedup vs baseline: 2.4615x; 1.0002x over previous
//
#include <hip/hip_runtime.h>

#define NN 20
#define ST 22          // stride for 20-row fp64 tiles; rows 16B-aligned (b128-friendly)
#define N2 400
#define MM 440
#define NITERS 25

// single-wave block + per-wave in-order LDS pipeline => compiler fence suffices
#define FENCE() asm volatile("" ::: "memory")

__device__ __forceinline__ double drcp(double x) {
  double r = __builtin_amdgcn_rcp(x);       // v_rcp_f64 seed (may be f16-grade)
  r = fma(r, fma(-x, r, 1.0), r);           // NR 1
  r = fma(r, fma(-x, r, 1.0), r);           // NR 2 -> ~1 ulp (1-NR was R5's failure)
  return r;
}
__device__ __forceinline__ double dreadlane(double v, int lane) {
  int lo = __builtin_amdgcn_readlane(__double2loint(v), lane);
  int hi = __builtin_amdgcn_readlane(__double2hiint(v), lane);
  return __hiloint2double(hi, lo);
}
__device__ __forceinline__ double wsumd(double v) {
#pragma unroll
  for (int off = 32; off > 0; off >>= 1) v += __shfl_xor(v, off, 64);
  return v;
}
__device__ __forceinline__ double fair_d(int c) {
  return (c < 8) ? 0.125 : (double)(-1.0f / 12.0f);  // matches fp32 ref constant
}

__global__ __launch_bounds__(64, 1) void ipm_kernel(const float* __restrict__ x,
                                                    float* __restrict__ out) {
  const int b = blockIdx.x;
  const int t = threadIdx.x;

  __shared__ __align__(16) double phim[NN * ST];   // phi row-major
  __shared__ __align__(16) double phimT[NN * ST];  // phi transposed
  __shared__ __align__(16) double y1m[NN * ST];
  __shared__ __align__(16) double y1T[NN * ST];
  __shared__ __align__(16) double SmX[ST * ST];    // rows 0..19: S (symmetric); rows 20/21: rb1/rb2
  __shared__ __align__(16) double D2vv[NN], p1v[NN], p2v[NN], D1iv[NN];
  __shared__ __align__(16) double bev[2 * NN];     // interleaved (be1[c], be2[c])

  const double EPSd = 1e-4, SIG = 0.1;

  // element state: element i = t + 64*j; s_slack == z exactly (identical updates)
  double zr[7], sl[7];
  double srs[7], rl[7], phir[7], y1r[7], du1[7], du2[7], dzr[7], sdl[7];
  int rr_[7], cc_[7];
  // row/col constraint state on lanes t<40 (rows 0..19, cols 20..39); r_pri == 0
  double s1 = 0.5, l1 = 1.0, rs1 = 0.0, ds1 = 0.0, dl1 = 0.0, invd = 0.0, gl1 = 0.0;
  double e0 = 0.0, e1 = 0.0, e2 = 0.0, D1iloc = 0.0;
  double W1 = 0.0, W2 = 0.0, sumdz = 0.0;

  // 2x2 Schur block decode (triangular, 55 blocks), once per kernel [R8-verified]
  int bc_, bp_;
  {
    int bid = t, c = 0;
#pragma unroll
    for (int q = 0; q < 9; ++q) {
      if (c < 9 && bid >= 10 - c) { bid -= 10 - c; ++c; }
    }
    bp_ = (t < 55) ? (c + bid) : 0;
    bc_ = (t < 55) ? c : 0;
  }

  double lreq0 = 0.0;
#pragma unroll
  for (int j = 0; j < 7; ++j) {
    int i = t + 64 * j;
    if (i < N2) {
      int r = i / NN, c = i - (i / NN) * NN;
      rr_[j] = r; cc_[j] = c;
      zr[j] = 0.025;
      sl[j] = 1.0;
      lreq0 += fair_d(c) * 0.025;
    } else { rr_[j] = 0; cc_[j] = 0; zr[j] = 0.025; sl[j] = 1.0; }
  }
  double req = wsumd(lreq0);
  double nu = 0.0;
  double musum = 30.0;                 // exact: 40*0.5 + 400*0.025
  double smu = SIG * musum * (1.0 / MM);

#pragma unroll 1
  for (int it = 0; it < NITERS; ++it) {
    // ---- C: prefetch p (L2-hot), per-constraint scalars, element recips
    float pf[7];
#pragma unroll
    for (int j = 0; j < 7; ++j) {
      int i = t + 64 * j;
      pf[j] = (i < N2) ? x[b * N2 + i] : 0.0f;
    }
    {
      double s1c = (t < 40) ? s1 : 1.0;
      double l1c = (t < 40) ? l1 : 1.0;
      rs1 = drcp(s1c);
      gl1 = smu * rs1;                 // valid on lanes <40
      invd = s1c * drcp(l1c);
    }
#pragma unroll
    for (int j = 0; j < 7; ++j) {
      srs[j] = drcp(zr[j]);                              // 1/s_slack (s==z)
      rl[j] = drcp(sl[j]);                               // 1/lam (for step ratios)
      phir[j] = zr[j] * drcp(fma(EPSd, zr[j], sl[j]));   // 1/(EPS + lam/s)
    }

    // ---- D: y1 = rhs_z; gl broadcast by shfl (full mask); store tiles
#pragma unroll
    for (int j = 0; j < 7; ++j) {
      int r = rr_[j], c = cc_[j];
      double glr = __shfl(gl1, r);
      double glc = __shfl(gl1, NN + c);
      int i = t + 64 * j;
      if (i < N2) {
        double pv = -(double)pf[j];
        double y = -(EPSd * zr[j] + pv + nu * fair_d(c)
                     + glr + glc - smu * srs[j]);
        y1r[j] = y;
        phim[r * ST + c] = phir[j];
        phimT[c * ST + r] = phir[j];
        y1m[r * ST + c] = y;
        y1T[c * ST + r] = y;
      }
    }
    FENCE();

    // ---- E: fused row (0..19) / col (20..39) reductions, contiguous double2
    if (t < 40) {
      const bool isrow = (t < NN);
      const int rc = isrow ? t : (t - NN);
      const double2* pb = reinterpret_cast<const double2*>(isrow ? &phim[rc * ST] : &phimT[rc * ST]);
      const double2* yb = reinterpret_cast<const double2*>(isrow ? &y1m[rc * ST] : &y1T[rc * ST]);
      double a0A = 0.0, a0B = 0.0, a1A = 0.0, a1B = 0.0, a2A = 0.0, a2B = 0.0;
#pragma unroll
      for (int jj = 0; jj < 10; ++jj) {
        double2 ph = pb[jj];
        double2 yy = yb[jj];
        a0A += ph.x;                 a0B += ph.y;
        a1A = fma(ph.x, yy.x, a1A);  a1B = fma(ph.y, yy.y, a1B);
        a2A = fma(ph.x, fair_d(2 * jj), a2A);
        a2B = fma(ph.y, fair_d(2 * jj + 1), a2B);
      }
      e0 = a0A + a0B; e1 = a1A + a1B; e2 = a2A + a2B;
      if (isrow) {
        D1iloc = drcp(invd + e0);
        D1iv[t] = D1iloc;            // read by G/I+J (phiD folding)
        p1v[t] = e1; p2v[t] = e2;
      } else {
        D2vv[rc] = invd + e0;
      }
    }
    FENCE();

    // ---- G: Schur via 2x2 triangular blocks; D1i folded into reads (F deleted)
    double g1loc = 0.0, g2loc = 0.0;
    {
      int cidx0 = NN + (t % NN);
      double t1c = __shfl(e1, cidx0);   // col-lane T1 for row lanes (full mask)
      double Ccl = __shfl(e0, cidx0);   // col-lane colsum(phi)
      const double2* d1p = reinterpret_cast<const double2*>(D1iv);
      if (t < 55) {
        const int c0 = 2 * bc_, c1i = 2 * bc_ + 1, q0 = 2 * bp_, q1i = 2 * bp_ + 1;
        const double2* pc0 = reinterpret_cast<const double2*>(&phimT[c0 * ST]);
        const double2* pc1 = reinterpret_cast<const double2*>(&phimT[c1i * ST]);
        const double2* pb0 = reinterpret_cast<const double2*>(&phimT[q0 * ST]);
        const double2* pb1 = reinterpret_cast<const double2*>(&phimT[q1i * ST]);
        double s00A = 0, s00B = 0, s01A = 0, s01B = 0;
        double s10A = 0, s10B = 0, s11A = 0, s11B = 0;
#pragma unroll
        for (int r = 0; r < 10; ++r) {
          double2 dd = d1p[r];
          double2 a0 = pc0[r], a1 = pc1[r], b0 = pb0[r], b1 = pb1[r];
          double u0x = a0.x * dd.x, u0y = a0.y * dd.y;   // = phiD[.][c0] (bit-exact vs F)
          double u1x = a1.x * dd.x, u1y = a1.y * dd.y;
          s00A = fma(u0x, b0.x, s00A); s00B = fma(u0y, b0.y, s00B);
          s01A = fma(u0x, b1.x, s01A); s01B = fma(u0y, b1.y, s01B);
          s10A = fma(u1x, b0.x, s10A); s10B = fma(u1y, b0.y, s10B);
          s11A = fma(u1x, b1.x, s11A); s11B = fma(u1y, b1.y, s11B);
        }
        double S00 = -(s00A + s00B), S01 = -(s01A + s01B);
        double S10 = -(s10A + s10B), S11 = -(s11A + s11B);
        if (bc_ == bp_) { S00 += D2vv[c0]; S11 += D2vv[c1i]; }
        SmX[c0 * ST + q0] = S00;  SmX[c0 * ST + q1i] = S01;
        SmX[c1i * ST + q0] = S10; SmX[c1i * ST + q1i] = S11;
        if (bc_ != bp_) {  // mirrors bit-exact (same products)
          SmX[q0 * ST + c0] = S00;  SmX[q1i * ST + c0] = S01;
          SmX[q0 * ST + c1i] = S10; SmX[q1i * ST + c1i] = S11;
        }
      }
      if (t < NN) {
        const double2* pa = reinterpret_cast<const double2*>(&phimT[t * ST]);
        const double2* q1 = reinterpret_cast<const double2*>(p1v);
        const double2* q2 = reinterpret_cast<const double2*>(p2v);
        double a1A = 0.0, a1B = 0.0, a2A = 0.0, a2B = 0.0;
#pragma unroll
        for (int r = 0; r < 10; ++r) {
          double2 dd = d1p[r];
          double2 u = pa[r];
          double ux = u.x * dd.x, uy = u.y * dd.y;       // phiD[.][t]
          double2 w1 = q1[r], w2 = q2[r];
          a1A = fma(ux, w1.x, a1A); a1B = fma(uy, w1.y, a1B);
          a2A = fma(ux, w2.x, a2A); a2B = fma(uy, w2.y, a2B);
        }
        g1loc = a1A + a1B; g2loc = a2A + a2B;
        SmX[20 * ST + t] = t1c - g1loc;                 // rb1 as row 20 (stride-1 write)
        SmX[21 * ST + t] = fair_d(t) * Ccl - g2loc;     // rb2 as row 21
      }
    }
    FENCE();

    // ---- H: 2x2 block Gauss-Jordan (10 pivot rounds); lane t owns column t
    {
      double B[NN];
      {
        int rowi = (t < NN + 2) ? t : 0;
        const double2* srcr = reinterpret_cast<const double2*>(&SmX[rowi * ST]);
#pragma unroll
        for (int k2 = 0; k2 < 10; ++k2) {
          double2 v = srcr[k2];
          B[2 * k2] = v.x; B[2 * k2 + 1] = v.y;
        }
      }
      // prime pivot block (0,1)
      double a = dreadlane(B[0], 0), bb = dreadlane(B[0], 1);
      double c = dreadlane(B[1], 0), d = dreadlane(B[1], 1);
      double rdet = drcp(fma(a, d, -(bb * c)));
#pragma unroll
      for (int p = 0; p < 10; ++p) {
        const int k = 2 * p;
        // scaled pivot rows: [rk; rk1] = Pinv * [row_k; row_k1]
        double t0 = d * B[k];       t0 = fma(-bb, B[k + 1], t0);
        double rk = t0 * rdet;
        double t1 = a * B[k + 1];   t1 = fma(-c, B[k], t1);
        double rk1 = t1 * rdet;
        if (p < 9) {
          // update next pivot rows first, then kick off next block's reciprocal
          double u0 = dreadlane(B[k + 2], k), u1 = dreadlane(B[k + 2], k + 1);
          B[k + 2] = fma(-u0, rk, B[k + 2]); B[k + 2] = fma(-u1, rk1, B[k + 2]);
          double v0 = dreadlane(B[k + 3], k), v1 = dreadlane(B[k + 3], k + 1);
          B[k + 3] = fma(-v0, rk, B[k + 3]); B[k + 3] = fma(-v1, rk1, B[k + 3]);
          a = dreadlane(B[k + 2], k + 2); bb = dreadlane(B[k + 2], k + 3);
          c = dreadlane(B[k + 3], k + 2); d = dreadlane(B[k + 3], k + 3);
          rdet = drcp(fma(a, d, -(bb * c)));   // latency hides under updates below
        }
#pragma unroll
        for (int i = 0; i < NN; ++i) {
          if (i != k && i != k + 1 && !(p < 9 && (i == k + 2 || i == k + 3))) {
            double ci0 = dreadlane(B[i], k), ci1 = dreadlane(B[i], k + 1);
            B[i] = fma(-ci0, rk, B[i]);
            B[i] = fma(-ci1, rk1, B[i]);
          }
        }
        B[k] = rk; B[k + 1] = rk1;
      }
      if (t == NN || t == NN + 1) {                // interleaved (be1[c],be2[c]) pairs
        int off = t - NN;
#pragma unroll
        for (int i = 0; i < NN; ++i) bev[2 * i + off] = B[i];
      }
    }
    FENCE();

    // ---- I+J merged: row pieces -> col pieces -> element w -> dnu (readlane sum)
    double PB1 = 0.0, PB2 = 0.0, a1rloc = 0.0, a2rloc = 0.0;
    {
      int cidx = (t >= NN && t < 2 * NN) ? (t - NN) : 0;
      double g1c = __shfl(g1loc, cidx);            // a1G[c] for col lanes (full mask)
      double g2c = __shfl(g2loc, cidx);
      const double2* d1p = reinterpret_cast<const double2*>(D1iv);
      if (t < NN) {
        const double2* pa = reinterpret_cast<const double2*>(&phim[t * ST]);
        const double2* bv = reinterpret_cast<const double2*>(bev);
        double b1A = 0.0, b1B = 0.0, b2A = 0.0, b2B = 0.0;
#pragma unroll
        for (int c2 = 0; c2 < 10; ++c2) {
          double2 ph = pa[c2];
          double2 e0b = bv[2 * c2];        // (be1[2c], be2[2c])
          double2 e1b = bv[2 * c2 + 1];    // (be1[2c+1], be2[2c+1])
          b1A = fma(ph.x, e0b.x, b1A); b2A = fma(ph.x, e0b.y, b2A);
          b1B = fma(ph.y, e1b.x, b1B); b2B = fma(ph.y, e1b.y, b2B);
        }
        PB1 = b1A + b1B; PB2 = b2A + b2B;
        a1rloc = (e1 - PB1) * D1iloc;
        a2rloc = (e2 - PB2) * D1iloc;
        W1 = e1 - e0 * a1rloc - PB1;
        W2 = e2 - e0 * a2rloc - PB2;
      }
      if (t >= NN && t < 2 * NN) {
        int c = t - NN;
        const double2* pa = reinterpret_cast<const double2*>(&phimT[c * ST]);
        double c1A = 0.0, c1B = 0.0, c2A = 0.0, c2B = 0.0;
#pragma unroll
        for (int r = 0; r < 10; ++r) {
          double2 dd = d1p[r];
          double2 u = pa[r];
          double ux = u.x * dd.x, uy = u.y * dd.y;   // phiD[.][c]
          double pb1x = dreadlane(PB1, 2 * r), pb1y = dreadlane(PB1, 2 * r + 1);
          double pb2x = dreadlane(PB2, 2 * r), pb2y = dreadlane(PB2, 2 * r + 1);
          c1A = fma(ux, pb1x, c1A); c1B = fma(uy, pb1y, c1B);
          c2A = fma(ux, pb2x, c2A); c2B = fma(uy, pb2y, c2B);
        }
        double A1 = g1c - (c1A + c1B);
        double A2 = g2c - (c2A + c2B);
        const double2* bv = reinterpret_cast<const double2*>(bev);
        double2 bec = bv[c];                       // (be1[c], be2[c])
        W1 = e1 - A1 - e0 * bec.x;                 // colsum(w1)
        W2 = e0 * fair_d(c) - A2 - e0 * bec.y;     // colsum(w2)
      }
    }
    // element w1/w2 (a_row via shfl, be via interleaved b128 read)
#pragma unroll
    for (int j = 0; j < 7; ++j) {
      double a1e = __shfl(a1rloc, rr_[j]);         // full mask
      double a2e = __shfl(a2rloc, rr_[j]);
      int i = t + 64 * j;
      if (i < N2) {
        const double2* bv = reinterpret_cast<const double2*>(bev);
        double2 bec = bv[cc_[j]];
        du1[j] = phir[j] * (y1r[j] - a1e - bec.x);
        du2[j] = phir[j] * (fair_d(cc_[j]) - a2e - bec.y);
      }
    }
    // dnu from col-lane colsums: l1 = sum_c fair[c]*W1[20+c] (exact reordering)
    double dnu;
    {
      double sA = 0.0, sB = 0.0, uA = 0.0, uB = 0.0;
#pragma unroll
      for (int c = 0; c < NN; c += 2) {
        sA = fma(fair_d(c),     dreadlane(W1, NN + c),     sA);
        sB = fma(fair_d(c + 1), dreadlane(W1, NN + c + 1), sB);
        uA = fma(fair_d(c),     dreadlane(W2, NN + c),     uA);
        uB = fma(fair_d(c + 1), dreadlane(W2, NN + c + 1), uB);
      }
      dnu = ((sA + sB) + req) * drcp(uA + uB);
    }
    if (t < 40) sumdz = W1 - dnu * W2;

    // ---- M: dz, dlam, branchless max-ratio, T1/T2; short tree (3 xor + 8 readlane)
    double maxr = 0.0, T1 = 0.0, T2 = 0.0;
    if (t < 40) {
      ds1 = -sumdz;                              // r_pri == 0
      dl1 = (smu - s1 * l1 - l1 * ds1) * rs1;
      maxr = fmax(maxr, -ds1 * rs1);             // = max(-ds/s)
      maxr = fmax(maxr, -dl1 * (rs1 * invd));    // rs1*invd = 1/lam
      T1 = s1 * dl1 + l1 * ds1;
      T2 = ds1 * dl1;
    }
#pragma unroll
    for (int j = 0; j < 7; ++j) {
      int i = t + 64 * j;
      if (i < N2) {
        double dz = du1[j] - dnu * du2[j];
        dzr[j] = dz;                             // ds_slack == dz
        double dl = (smu - zr[j] * sl[j] - sl[j] * dz) * srs[j];
        sdl[j] = dl;
        maxr = fmax(maxr, -dz * srs[j]);
        maxr = fmax(maxr, -dl * rl[j]);
        T1 += zr[j] * dl + sl[j] * dz;
        T2 += dz * dl;
      }
    }
#pragma unroll
    for (int off = 32; off >= 8; off >>= 1) {    // lanes t: reduced over {t + 8k}
      maxr = fmax(maxr, __shfl_xor(maxr, off, 64));
      T1 += __shfl_xor(T1, off, 64);
      T2 += __shfl_xor(T2, off, 64);
    }
    {
      double m0 = 0.0, sT1A = 0.0, sT1B = 0.0, sT2A = 0.0, sT2B = 0.0;
#pragma unroll
      for (int l = 0; l < 8; l += 2) {           // combine the 8 residue classes
        m0 = fmax(m0, fmax(dreadlane(maxr, l), dreadlane(maxr, l + 1)));
        sT1A += dreadlane(T1, l); sT1B += dreadlane(T1, l + 1);
        sT2A += dreadlane(T2, l); sT2B += dreadlane(T2, l + 1);
      }
      maxr = m0; T1 = sT1A + sT1B; T2 = sT2A + sT2B;
    }
    const double alpha = fmin(1.0, 0.99 * drcp(maxr));  // maxr==0 -> inf -> 1

    // ---- N: updates + exact recurrences (mu, req)
#pragma unroll
    for (int j = 0; j < 7; ++j) {
      int i = t + 64 * j;
      if (i < N2) {
        zr[j] = fma(alpha, dzr[j], zr[j]);
        sl[j] = fma(alpha, sdl[j], sl[j]);
      }
    }
    if (t < 40) {
      s1 = fma(alpha, ds1, s1);
      l1 = fma(alpha, dl1, l1);
    }
    nu = fma(alpha, dnu, nu);
    req *= (1.0 - alpha);
    musum = fma(alpha * alpha, T2, fma(alpha, T1, musum));
    smu = SIG * musum * (1.0 / MM);
    FENCE();
  }

#pragma unroll
  for (int j = 0; j < 7; ++j) {
    int i = t + 64 * j;
    if (i < N2) out[b * N2 + i] = (float)zr[j];
  }
}

extern "C" void kernel_launch(void* const* d_in, const int* in_sizes, int n_in,
                              void* d_out, int out_size, void* d_ws, size_t ws_size,
                              hipStream_t stream) {
  const float* x = (const float*)d_in[0];
  float* out = (float*)d_out;
  hipLaunchKernelGGL(ipm_kernel, dim3(32), dim3(64), 0, stream, x, out);
}

// Round 11
// 252.781 us; speedup vs baseline: 2.7647x; 1.1232x over previous
//
#include <hip/hip_runtime.h>

#define NN 20
#define ST 22          // stride for 20-row fp64 tiles; rows 16B-aligned (b128-friendly)
#define N2 400
#define MM 440
#define NITERS 25

// single-wave block + per-wave in-order LDS pipeline => compiler fence suffices
#define FENCE() asm volatile("" ::: "memory")

__device__ __forceinline__ double drcp(double x) {
  double r = __builtin_amdgcn_rcp(x);       // v_rcp_f64 seed (may be f16-grade)
  r = fma(r, fma(-x, r, 1.0), r);           // NR 1
  r = fma(r, fma(-x, r, 1.0), r);           // NR 2 -> ~1 ulp (1-NR was R5's failure)
  return r;
}
__device__ __forceinline__ double dreadlane(double v, int lane) {
  int lo = __builtin_amdgcn_readlane(__double2loint(v), lane);
  int hi = __builtin_amdgcn_readlane(__double2hiint(v), lane);
  return __hiloint2double(hi, lo);
}
__device__ __forceinline__ double wsumd(double v) {
#pragma unroll
  for (int off = 32; off > 0; off >>= 1) v += __shfl_xor(v, off, 64);
  return v;
}
__device__ __forceinline__ double fair_d(int c) {
  return (c < 8) ? 0.125 : (double)(-1.0f / 12.0f);  // matches fp32 ref constant
}

__global__ __launch_bounds__(64, 1) void ipm_kernel(const float* __restrict__ x,
                                                    float* __restrict__ out) {
  const int b = blockIdx.x;
  const int t = threadIdx.x;

  __shared__ __align__(16) double phim[NN * ST];   // phi row-major
  __shared__ __align__(16) double phimT[NN * ST];  // phi transposed
  __shared__ __align__(16) double y1m[NN * ST];
  __shared__ __align__(16) double y1T[NN * ST];
  __shared__ __align__(16) double SmX[ST * ST];    // rows 0..19: S (symmetric); rows 20/21: rb1/rb2
  __shared__ __align__(16) double bev[2 * NN];     // interleaved (be1[c], be2[c])

  const double EPSd = 1e-4, SIG = 0.1;

  // element state: element i = t + 64*j; s_slack == z exactly (identical updates)
  double zr[7], sl[7];
  double srs[7], rl[7], phir[7], y1r[7], du1[7], du2[7], dzr[7], sdl[7];
  int rr_[7], cc_[7];
  // row/col constraint state on lanes t<40 (rows 0..19, cols 20..39); r_pri == 0
  double s1 = 0.5, l1 = 1.0, rs1 = 0.0, ds1 = 0.0, dl1 = 0.0, invd = 0.0, gl1 = 0.0;
  double e0 = 0.0, e1 = 0.0, e2 = 0.0, D1iloc = 0.0;
  double W1 = 0.0, W2 = 0.0, sumdz = 0.0;

  // 2x2 Schur block decode (triangular, 55 blocks), once per kernel [R8-verified]
  int bc_, bp_;
  {
    int bid = t, c = 0;
#pragma unroll
    for (int q = 0; q < 9; ++q) {
      if (c < 9 && bid >= 10 - c) { bid -= 10 - c; ++c; }
    }
    bp_ = (t < 55) ? (c + bid) : 0;
    bc_ = (t < 55) ? c : 0;
  }

  double lreq0 = 0.0;
#pragma unroll
  for (int j = 0; j < 7; ++j) {
    int i = t + 64 * j;
    if (i < N2) {
      int r = i / NN, c = i - (i / NN) * NN;
      rr_[j] = r; cc_[j] = c;
      zr[j] = 0.025;
      sl[j] = 1.0;
      lreq0 += fair_d(c) * 0.025;
    } else { rr_[j] = 0; cc_[j] = 0; zr[j] = 0.025; sl[j] = 1.0; }
  }
  double req = wsumd(lreq0);
  double nu = 0.0;
  double musum = 30.0;                 // exact: 40*0.5 + 400*0.025
  double smu = SIG * musum * (1.0 / MM);

#pragma unroll 1
  for (int it = 0; it < NITERS; ++it) {
    // ---- C: prefetch p (L2-hot), per-constraint scalars, element recips
    float pf[7];
#pragma unroll
    for (int j = 0; j < 7; ++j) {
      int i = t + 64 * j;
      pf[j] = (i < N2) ? x[b * N2 + i] : 0.0f;
    }
    {
      double s1c = (t < 40) ? s1 : 1.0;
      double l1c = (t < 40) ? l1 : 1.0;
      rs1 = drcp(s1c);
      gl1 = smu * rs1;                 // valid on lanes <40
      invd = s1c * drcp(l1c);
    }
#pragma unroll
    for (int j = 0; j < 7; ++j) {
      srs[j] = drcp(zr[j]);                              // 1/s_slack (s==z)
      rl[j] = drcp(sl[j]);                               // 1/lam (for step ratios)
      phir[j] = zr[j] * drcp(fma(EPSd, zr[j], sl[j]));   // 1/(EPS + lam/s)
    }

    // ---- D: y1 = rhs_z; gl broadcast by shfl (full mask); store tiles
#pragma unroll
    for (int j = 0; j < 7; ++j) {
      int r = rr_[j], c = cc_[j];
      double glr = __shfl(gl1, r);
      double glc = __shfl(gl1, NN + c);
      int i = t + 64 * j;
      if (i < N2) {
        double pv = -(double)pf[j];
        double y = -(EPSd * zr[j] + pv + nu * fair_d(c)
                     + glr + glc - smu * srs[j]);
        y1r[j] = y;
        phim[r * ST + c] = phir[j];
        phimT[c * ST + r] = phir[j];
        y1m[r * ST + c] = y;
        y1T[c * ST + r] = y;
      }
    }
    FENCE();

    // ---- E+G merged (single fence): reductions, then Schur — small vectors
    //      (D1i, p1, p2, D2) travel by readlane/shfl, never through LDS.
    if (t < 40) {
      const bool isrow = (t < NN);
      const int rc = isrow ? t : (t - NN);
      const double2* pb = reinterpret_cast<const double2*>(isrow ? &phim[rc * ST] : &phimT[rc * ST]);
      const double2* yb = reinterpret_cast<const double2*>(isrow ? &y1m[rc * ST] : &y1T[rc * ST]);
      double a0A = 0.0, a0B = 0.0, a1A = 0.0, a1B = 0.0, a2A = 0.0, a2B = 0.0;
#pragma unroll
      for (int jj = 0; jj < 10; ++jj) {
        double2 ph = pb[jj];
        double2 yy = yb[jj];
        a0A += ph.x;                 a0B += ph.y;
        a1A = fma(ph.x, yy.x, a1A);  a1B = fma(ph.y, yy.y, a1B);
        a2A = fma(ph.x, fair_d(2 * jj), a2A);
        a2B = fma(ph.y, fair_d(2 * jj + 1), a2B);
      }
      e0 = a0A + a0B; e1 = a1A + a1B; e2 = a2A + a2B;
      if (isrow) D1iloc = drcp(invd + e0);
    }
    // D2 diagonal + col-lane scalars for rb rows (full-mask dynamic shfl)
    double g1loc = 0.0, g2loc = 0.0;
    {
      double D2loc = invd + e0;                // meaningful on lanes 20..39
      double D2c0 = __shfl(D2loc, NN + 2 * bc_);
      double D2c1 = __shfl(D2loc, NN + 2 * bc_ + 1);
      int cidx0 = NN + (t % NN);
      double t1c = __shfl(e1, cidx0);          // col-lane T1 for row lanes
      double Ccl = __shfl(e0, cidx0);          // col-lane colsum(phi)
      if (t < 55) {
        const int c0 = 2 * bc_, c1i = 2 * bc_ + 1, q0 = 2 * bp_, q1i = 2 * bp_ + 1;
        const double2* pc0 = reinterpret_cast<const double2*>(&phimT[c0 * ST]);
        const double2* pc1 = reinterpret_cast<const double2*>(&phimT[c1i * ST]);
        const double2* pb0 = reinterpret_cast<const double2*>(&phimT[q0 * ST]);
        const double2* pb1 = reinterpret_cast<const double2*>(&phimT[q1i * ST]);
        double s00A = 0, s00B = 0, s01A = 0, s01B = 0;
        double s10A = 0, s10B = 0, s11A = 0, s11B = 0;
#pragma unroll
        for (int r = 0; r < 10; ++r) {
          double ddx = dreadlane(D1iloc, 2 * r);       // row-lane D1i, reg path
          double ddy = dreadlane(D1iloc, 2 * r + 1);
          double2 a0 = pc0[r], a1 = pc1[r], b0 = pb0[r], b1 = pb1[r];
          double u0x = a0.x * ddx, u0y = a0.y * ddy;   // = phiD[.][c0] (bit-exact)
          double u1x = a1.x * ddx, u1y = a1.y * ddy;
          s00A = fma(u0x, b0.x, s00A); s00B = fma(u0y, b0.y, s00B);
          s01A = fma(u0x, b1.x, s01A); s01B = fma(u0y, b1.y, s01B);
          s10A = fma(u1x, b0.x, s10A); s10B = fma(u1y, b0.y, s10B);
          s11A = fma(u1x, b1.x, s11A); s11B = fma(u1y, b1.y, s11B);
        }
        double S00 = -(s00A + s00B), S01 = -(s01A + s01B);
        double S10 = -(s10A + s10B), S11 = -(s11A + s11B);
        if (bc_ == bp_) { S00 += D2c0; S11 += D2c1; }
        SmX[c0 * ST + q0] = S00;  SmX[c0 * ST + q1i] = S01;
        SmX[c1i * ST + q0] = S10; SmX[c1i * ST + q1i] = S11;
        if (bc_ != bp_) {  // mirrors bit-exact (same products)
          SmX[q0 * ST + c0] = S00;  SmX[q1i * ST + c0] = S01;
          SmX[q0 * ST + c1i] = S10; SmX[q1i * ST + c1i] = S11;
        }
      }
      if (t < NN) {
        const double2* pa = reinterpret_cast<const double2*>(&phimT[t * ST]);
        double a1A = 0.0, a1B = 0.0, a2A = 0.0, a2B = 0.0;
#pragma unroll
        for (int r = 0; r < 10; ++r) {
          double ddx = dreadlane(D1iloc, 2 * r);
          double ddy = dreadlane(D1iloc, 2 * r + 1);
          double2 u = pa[r];
          double ux = u.x * ddx, uy = u.y * ddy;       // phiD[.][t]
          double p1x = dreadlane(e1, 2 * r), p1y = dreadlane(e1, 2 * r + 1);
          double p2x = dreadlane(e2, 2 * r), p2y = dreadlane(e2, 2 * r + 1);
          a1A = fma(ux, p1x, a1A); a1B = fma(uy, p1y, a1B);
          a2A = fma(ux, p2x, a2A); a2B = fma(uy, p2y, a2B);
        }
        g1loc = a1A + a1B; g2loc = a2A + a2B;
        SmX[20 * ST + t] = t1c - g1loc;                 // rb1 as row 20 (stride-1 write)
        SmX[21 * ST + t] = fair_d(t) * Ccl - g2loc;     // rb2 as row 21
      }
    }
    FENCE();

    // ---- H: 2x2 block Gauss-Jordan (10 pivot rounds); lane t owns column t
    {
      double B[NN];
      {
        int rowi = (t < NN + 2) ? t : 0;
        const double2* srcr = reinterpret_cast<const double2*>(&SmX[rowi * ST]);
#pragma unroll
        for (int k2 = 0; k2 < 10; ++k2) {
          double2 v = srcr[k2];
          B[2 * k2] = v.x; B[2 * k2 + 1] = v.y;
        }
      }
      // prime pivot block (0,1)
      double a = dreadlane(B[0], 0), bb = dreadlane(B[0], 1);
      double c = dreadlane(B[1], 0), d = dreadlane(B[1], 1);
      double rdet = drcp(fma(a, d, -(bb * c)));
#pragma unroll
      for (int p = 0; p < 10; ++p) {
        const int k = 2 * p;
        // scaled pivot rows: [rk; rk1] = Pinv * [row_k; row_k1]
        double t0 = d * B[k];       t0 = fma(-bb, B[k + 1], t0);
        double rk = t0 * rdet;
        double t1 = a * B[k + 1];   t1 = fma(-c, B[k], t1);
        double rk1 = t1 * rdet;
        if (p < 9) {
          // update next pivot rows first, then kick off next block's reciprocal
          double u0 = dreadlane(B[k + 2], k), u1 = dreadlane(B[k + 2], k + 1);
          B[k + 2] = fma(-u0, rk, B[k + 2]); B[k + 2] = fma(-u1, rk1, B[k + 2]);
          double v0 = dreadlane(B[k + 3], k), v1 = dreadlane(B[k + 3], k + 1);
          B[k + 3] = fma(-v0, rk, B[k + 3]); B[k + 3] = fma(-v1, rk1, B[k + 3]);
          a = dreadlane(B[k + 2], k + 2); bb = dreadlane(B[k + 2], k + 3);
          c = dreadlane(B[k + 3], k + 2); d = dreadlane(B[k + 3], k + 3);
          rdet = drcp(fma(a, d, -(bb * c)));   // latency hides under updates below
        }
#pragma unroll
        for (int i = 0; i < NN; ++i) {
          if (i != k && i != k + 1 && !(p < 9 && (i == k + 2 || i == k + 3))) {
            double ci0 = dreadlane(B[i], k), ci1 = dreadlane(B[i], k + 1);
            B[i] = fma(-ci0, rk, B[i]);
            B[i] = fma(-ci1, rk1, B[i]);
          }
        }
        B[k] = rk; B[k + 1] = rk1;
      }
      if (t == NN || t == NN + 1) {                // interleaved (be1[c],be2[c]) pairs
        int off = t - NN;
#pragma unroll
        for (int i = 0; i < NN; ++i) bev[2 * i + off] = B[i];
      }
    }
    FENCE();

    // ---- I+J merged: row pieces -> col pieces -> element w -> dnu (readlane sum)
    double PB1 = 0.0, PB2 = 0.0, a1rloc = 0.0, a2rloc = 0.0;
    {
      int cidx = (t >= NN && t < 2 * NN) ? (t - NN) : 0;
      double g1c = __shfl(g1loc, cidx);            // a1G[c] for col lanes (full mask)
      double g2c = __shfl(g2loc, cidx);
      if (t < NN) {
        const double2* pa = reinterpret_cast<const double2*>(&phim[t * ST]);
        const double2* bv = reinterpret_cast<const double2*>(bev);
        double b1A = 0.0, b1B = 0.0, b2A = 0.0, b2B = 0.0;
#pragma unroll
        for (int c2 = 0; c2 < 10; ++c2) {
          double2 ph = pa[c2];
          double2 e0b = bv[2 * c2];        // (be1[2c], be2[2c])
          double2 e1b = bv[2 * c2 + 1];    // (be1[2c+1], be2[2c+1])
          b1A = fma(ph.x, e0b.x, b1A); b2A = fma(ph.x, e0b.y, b2A);
          b1B = fma(ph.y, e1b.x, b1B); b2B = fma(ph.y, e1b.y, b2B);
        }
        PB1 = b1A + b1B; PB2 = b2A + b2B;
        a1rloc = (e1 - PB1) * D1iloc;
        a2rloc = (e2 - PB2) * D1iloc;
        W1 = e1 - e0 * a1rloc - PB1;
        W2 = e2 - e0 * a2rloc - PB2;
      }
      if (t >= NN && t < 2 * NN) {
        int c = t - NN;
        const double2* pa = reinterpret_cast<const double2*>(&phimT[c * ST]);
        double c1A = 0.0, c1B = 0.0, c2A = 0.0, c2B = 0.0;
#pragma unroll
        for (int r = 0; r < 10; ++r) {
          double ddx = dreadlane(D1iloc, 2 * r);
          double ddy = dreadlane(D1iloc, 2 * r + 1);
          double2 u = pa[r];
          double ux = u.x * ddx, uy = u.y * ddy;   // phiD[.][c]
          double pb1x = dreadlane(PB1, 2 * r), pb1y = dreadlane(PB1, 2 * r + 1);
          double pb2x = dreadlane(PB2, 2 * r), pb2y = dreadlane(PB2, 2 * r + 1);
          c1A = fma(ux, pb1x, c1A); c1B = fma(uy, pb1y, c1B);
          c2A = fma(ux, pb2x, c2A); c2B = fma(uy, pb2y, c2B);
        }
        double A1 = g1c - (c1A + c1B);
        double A2 = g2c - (c2A + c2B);
        const double2* bv = reinterpret_cast<const double2*>(bev);
        double2 bec = bv[c];                       // (be1[c], be2[c])
        W1 = e1 - A1 - e0 * bec.x;                 // colsum(w1)
        W2 = e0 * fair_d(c) - A2 - e0 * bec.y;     // colsum(w2)
      }
    }
    // element w1/w2 (a_row via shfl, be via interleaved b128 read)
#pragma unroll
    for (int j = 0; j < 7; ++j) {
      double a1e = __shfl(a1rloc, rr_[j]);         // full mask
      double a2e = __shfl(a2rloc, rr_[j]);
      int i = t + 64 * j;
      if (i < N2) {
        const double2* bv = reinterpret_cast<const double2*>(bev);
        double2 bec = bv[cc_[j]];
        du1[j] = phir[j] * (y1r[j] - a1e - bec.x);
        du2[j] = phir[j] * (fair_d(cc_[j]) - a2e - bec.y);
      }
    }
    // dnu from col-lane colsums: l1 = sum_c fair[c]*W1[20+c] (exact reordering)
    double dnu;
    {
      double sA = 0.0, sB = 0.0, uA = 0.0, uB = 0.0;
#pragma unroll
      for (int c = 0; c < NN; c += 2) {
        sA = fma(fair_d(c),     dreadlane(W1, NN + c),     sA);
        sB = fma(fair_d(c + 1), dreadlane(W1, NN + c + 1), sB);
        uA = fma(fair_d(c),     dreadlane(W2, NN + c),     uA);
        uB = fma(fair_d(c + 1), dreadlane(W2, NN + c + 1), uB);
      }
      dnu = ((sA + sB) + req) * drcp(uA + uB);
    }
    if (t < 40) sumdz = W1 - dnu * W2;

    // ---- M: dz, dlam, branchless max-ratio, T1/T2; short tree (3 xor + 8 readlane)
    double maxr = 0.0, T1 = 0.0, T2 = 0.0;
    if (t < 40) {
      ds1 = -sumdz;                              // r_pri == 0
      dl1 = (smu - s1 * l1 - l1 * ds1) * rs1;
      maxr = fmax(maxr, -ds1 * rs1);             // = max(-ds/s)
      maxr = fmax(maxr, -dl1 * (rs1 * invd));    // rs1*invd = 1/lam
      T1 = s1 * dl1 + l1 * ds1;
      T2 = ds1 * dl1;
    }
#pragma unroll
    for (int j = 0; j < 7; ++j) {
      int i = t + 64 * j;
      if (i < N2) {
        double dz = du1[j] - dnu * du2[j];
        dzr[j] = dz;                             // ds_slack == dz
        double dl = (smu - zr[j] * sl[j] - sl[j] * dz) * srs[j];
        sdl[j] = dl;
        maxr = fmax(maxr, -dz * srs[j]);
        maxr = fmax(maxr, -dl * rl[j]);
        T1 += zr[j] * dl + sl[j] * dz;
        T2 += dz * dl;
      }
    }
#pragma unroll
    for (int off = 32; off >= 8; off >>= 1) {    // lanes t: reduced over {t + 8k}
      maxr = fmax(maxr, __shfl_xor(maxr, off, 64));
      T1 += __shfl_xor(T1, off, 64);
      T2 += __shfl_xor(T2, off, 64);
    }
    {
      double m0 = 0.0, sT1A = 0.0, sT1B = 0.0, sT2A = 0.0, sT2B = 0.0;
#pragma unroll
      for (int l = 0; l < 8; l += 2) {           // combine the 8 residue classes
        m0 = fmax(m0, fmax(dreadlane(maxr, l), dreadlane(maxr, l + 1)));
        sT1A += dreadlane(T1, l); sT1B += dreadlane(T1, l + 1);
        sT2A += dreadlane(T2, l); sT2B += dreadlane(T2, l + 1);
      }
      maxr = m0; T1 = sT1A + sT1B; T2 = sT2A + sT2B;
    }
    const double alpha = fmin(1.0, 0.99 * drcp(maxr));  // maxr==0 -> inf -> 1

    // ---- N: updates + exact recurrences (mu, req)
#pragma unroll
    for (int j = 0; j < 7; ++j) {
      int i = t + 64 * j;
      if (i < N2) {
        zr[j] = fma(alpha, dzr[j], zr[j]);
        sl[j] = fma(alpha, sdl[j], sl[j]);
      }
    }
    if (t < 40) {
      s1 = fma(alpha, ds1, s1);
      l1 = fma(alpha, dl1, l1);
    }
    nu = fma(alpha, dnu, nu);
    req *= (1.0 - alpha);
    musum = fma(alpha * alpha, T2, fma(alpha, T1, musum));
    smu = SIG * musum * (1.0 / MM);
    FENCE();
  }

#pragma unroll
  for (int j = 0; j < 7; ++j) {
    int i = t + 64 * j;
    if (i < N2) out[b * N2 + i] = (float)zr[j];
  }
}

extern "C" void kernel_launch(void* const* d_in, const int* in_sizes, int n_in,
                              void* d_out, int out_size, void* d_ws, size_t ws_size,
                              hipStream_t stream) {
  const float* x = (const float*)d_in[0];
  float* out = (float*)d_out;
  hipLaunchKernelGGL(ipm_kernel, dim3(32), dim3(64), 0, stream, x, out);
}